// Round 6
// baseline (394.901 us; speedup 1.0000x reference)
//
#include <hip/hip_runtime.h>
#include <stdint.h>

typedef unsigned short u16;
typedef __bf16  bf16x8   __attribute__((ext_vector_type(8)));
typedef float   floatx4  __attribute__((ext_vector_type(4)));
typedef float   floatx16 __attribute__((ext_vector_type(16)));
typedef unsigned short ushortx4 __attribute__((ext_vector_type(4)));

__device__ __forceinline__ u16 f2bf(float f) {
  unsigned u = __builtin_bit_cast(unsigned, f);
  u += 0x7FFFu + ((u >> 16) & 1u);           // RNE; inputs are finite
  return (u16)(u >> 16);
}

#define GLD_LDS16(g, l)                                                        \
  __builtin_amdgcn_global_load_lds(                                            \
      (const __attribute__((address_space(1))) void*)(g),                      \
      (__attribute__((address_space(3))) void*)(l), 16, 0, 0)

// Raw barriers that do NOT drain vmcnt(0) — keeps prefetch DMA in flight.
#define BAR_LGKM()      asm volatile("s_waitcnt lgkmcnt(0)\ns_barrier" ::: "memory")
#define BAR_VM8()       asm volatile("s_waitcnt vmcnt(8)\ns_barrier" ::: "memory")
#define BAR_LGKM_VM4()  asm volatile("s_waitcnt lgkmcnt(0) vmcnt(4)\ns_barrier" ::: "memory")

// ---------------------------------------------------------------------------
// Kernel 0: weights fp32 -> bf16 (unchanged; works).
// ---------------------------------------------------------------------------
__global__ __launch_bounds__(256) void cvt_w(
    const float* __restrict__ Wq, const float* __restrict__ Wk,
    const float* __restrict__ Wv, u16* __restrict__ dst)
{
  const int z = blockIdx.y;
  const float* src = (z == 0) ? Wq : (z == 1) ? Wk : Wv;
  u16* d = dst + (size_t)z * 262144;
  const int idx = (blockIdx.x * 256 + threadIdx.x) * 8;
  const float4 lo = *(const float4*)&src[idx];
  const float4 hi = *(const float4*)&src[idx + 4];
  union { u16 h[8]; uint4 v; } pk;
  pk.h[0] = f2bf(lo.x); pk.h[1] = f2bf(lo.y); pk.h[2] = f2bf(lo.z); pk.h[3] = f2bf(lo.w);
  pk.h[4] = f2bf(hi.x); pk.h[5] = f2bf(hi.y); pk.h[6] = f2bf(hi.z); pk.h[7] = f2bf(hi.w);
  *(uint4*)&d[idx] = pk.v;
}

// ---------------------------------------------------------------------------
// Kernel 1: fused QKV projection (unchanged from r4/r5; verified).
// K/V^T written frag-major swizzled; q row-major pre-scaled by log2e/sqrt(512).
// ---------------------------------------------------------------------------
__global__ __launch_bounds__(256, 2) void qkv_gemm(
    const float* __restrict__ X, const u16* __restrict__ Wb,
    u16* __restrict__ qo, u16* __restrict__ ksw, u16* __restrict__ vsw)
{
  __shared__ u16 As[128 * 32];
  __shared__ u16 Bs[128 * 32];

  const int tid = threadIdx.x;
  const int w  = tid >> 6, l = tid & 63;
  const int lr = l & 15, lq = l >> 4;
  const int lk = lq * 8;
  const int m0 = blockIdx.x * 128;
  const int n0 = blockIdx.y * 128;
  const int z  = blockIdx.z;
  const u16* W = Wb + (size_t)z * 262144;
  const int wm = (w & 1) * 64, wn = (w >> 1) * 64;

  floatx4 acc[4][4];
  const floatx4 fz = {0.f, 0.f, 0.f, 0.f};
#pragma unroll
  for (int i = 0; i < 4; ++i)
#pragma unroll
    for (int j = 0; j < 4; ++j) acc[i][j] = fz;

  for (int kk = 0; kk < 512; kk += 32) {
    __syncthreads();
#pragma unroll
    for (int i = 0; i < 2; ++i) {
      const int c   = tid * 2 + i;
      const int row = c >> 2;
      const int c8  = (c & 3) * 8;
      const float4 lo = *(const float4*)&X[(size_t)(m0 + row) * 512 + kk + c8];
      const float4 hi = *(const float4*)&X[(size_t)(m0 + row) * 512 + kk + c8 + 4];
      union { u16 h[8]; uint4 v; } pk;
      pk.h[0] = f2bf(lo.x); pk.h[1] = f2bf(lo.y); pk.h[2] = f2bf(lo.z); pk.h[3] = f2bf(lo.w);
      pk.h[4] = f2bf(hi.x); pk.h[5] = f2bf(hi.y); pk.h[6] = f2bf(hi.z); pk.h[7] = f2bf(hi.w);
      *(uint4*)&As[c * 8] = pk.v;
    }
#pragma unroll
    for (int i = 0; i < 2; ++i) {
      const int c = i * 256 + tid;
      GLD_LDS16(W + (size_t)(n0 + (c >> 2)) * 512 + kk + (c & 3) * 8, &Bs[c * 8]);
    }
    __syncthreads();

    bf16x8 af[4], bfr[4];
#pragma unroll
    for (int t = 0; t < 4; ++t) {
      af[t]  = *(const bf16x8*)&As[(wm + t * 16 + lr) * 32 + lk];
      bfr[t] = *(const bf16x8*)&Bs[(wn + t * 16 + lr) * 32 + lk];
    }
#pragma unroll
    for (int i = 0; i < 4; ++i)
#pragma unroll
      for (int j = 0; j < 4; ++j)
        acc[i][j] = __builtin_amdgcn_mfma_f32_16x16x32_bf16(af[i], bfr[j],
                                                            acc[i][j], 0, 0, 0);
  }

  const int cr = lq * 4;   // C layout: col=lane&15, row=quad*4+reg
  if (z == 2) {
#pragma unroll
    for (int i = 0; i < 4; ++i)
#pragma unroll
      for (int j = 0; j < 4; ++j) {
        const int n = n0 + wn + j * 16 + lr;           // d
        const int m = m0 + wm + i * 16 + cr;           // first key (b*4096+s)
        const int b = m >> 12, s = m & 4095;
        const int t = s >> 5, s5 = s & 31;
        const int dh = n >> 8, dl = n & 255;
        const size_t chunk = ((size_t)(b * 128 + t) * 2 + dh) * 1024
                           + (dl >> 5) * 128 + ((s5 >> 4) & 1) * 64
                           + ((s5 >> 3) & 1) * 32 + (dl & 31);
        ushortx4 pk;
#pragma unroll
        for (int r = 0; r < 4; ++r) pk[r] = f2bf(acc[i][j][r]);
        *(ushortx4*)&vsw[chunk * 8 + (cr & 7)] = pk;
      }
  } else if (z == 1) {
#pragma unroll
    for (int i = 0; i < 4; ++i)
#pragma unroll
      for (int j = 0; j < 4; ++j) {
        const int n = n0 + wn + j * 16 + lr;           // d
        const int m = m0 + wm + i * 16 + cr;           // key
        const int b = m >> 12, s = m & 4095;
        const int t = s >> 5, s5 = s & 31;
        const size_t base = (size_t)(b * 128 + t) * 2048
                          + (n >> 4) * 64 + ((n >> 3) & 1) * 32 + s5;
#pragma unroll
        for (int r = 0; r < 4; ++r)
          ksw[(base + r) * 8 + (n & 7)] = f2bf(acc[i][j][r]);
      }
  } else {
    const float sc = 0.06375871732f;                   // log2(e)/sqrt(512)
#pragma unroll
    for (int i = 0; i < 4; ++i)
#pragma unroll
      for (int j = 0; j < 4; ++j) {
        const int m = m0 + wm + i * 16 + cr;
        const int n = n0 + wn + j * 16 + lr;
#pragma unroll
        for (int r = 0; r < 4; ++r)
          qo[(size_t)(m + r) * 512 + n] = f2bf(acc[i][j][r] * sc);
      }
  }
}

// ---------------------------------------------------------------------------
// Kernel 2: flash attention v6 — software-pipelined DMA.
// Grid 256 (1 WG/CU), 512 thr = 8 waves (qs in {0,1} q-subtile, dq in {0..3}).
// Per 32-key iter: QK k-split 4-way (8 MFMA/wave, partials exchanged as fp32
// through 8 LDS regions, stride-34 dwords: conflict-free writes + b64 reads);
// every wave rebuilds full P in registers (exp2, static max) -> PV 4-way
// D-split (8 MFMA/wave).  (qs,dq) owns disjoint O block -> no merge.
// DMA pipeline: K double-buffered (prefetch distance 1), V single-buffered
// (issued at top, drains over QK+exchange).  In-loop barriers are raw asm
// s_waitcnt vmcnt(8)/vmcnt(4)+lgkmcnt(0); NEVER vmcnt(0) -> prefetch
// survives barriers (vmcnt retires in-order, so vmcnt(8) == K(p) landed).
// LDS 133120 B: Kbuf 2x32K | Vbuf 32K | 8 x 4352 exchange.
// ---------------------------------------------------------------------------
__global__ __launch_bounds__(512, 2) void attn(
    const u16* __restrict__ q, const u16* __restrict__ ksw,
    const u16* __restrict__ vsw, float* __restrict__ out)
{
  extern __shared__ u16 smem[];
  const int tid = threadIdx.x;
  const int w  = tid >> 6, L = tid & 63;
  const int Ln = L & 31, Lh = L >> 5;
  const int qs = w >> 2, dq = w & 3;
  const int g  = blockIdx.x;
  const int b  = (g & 7) >> 1;                  // XCD-locality: same b per XCD
  const int qt = ((g >> 3) << 1) | (g & 1);     // 0..63

  u16* Vb = smem + 32768;                       // u16 idx; Kbuf0=0, Kbuf1=16384
  float* myreg = (float*)(smem + 49152 + (qs * 4 + dq) * 2176);
  const float* r0 = (const float*)(smem + 49152 + (qs * 4 + 0) * 2176);
  const float* r1 = (const float*)(smem + 49152 + (qs * 4 + 1) * 2176);
  const float* r2 = (const float*)(smem + 49152 + (qs * 4 + 2) * 2176);
  const float* r3 = (const float*)(smem + 49152 + (qs * 4 + 3) * 2176);

  // ---- Q A-frags for this wave's 128-D k-range: 8 x bf16x8 (32 VGPR) ----
  bf16x8 qf[8];
  {
    const u16* qb = q + ((size_t)(b * 4096 + qt * 64 + qs * 32 + Ln)) * 512
                    + dq * 128 + Lh * 8;
#pragma unroll
    for (int m = 0; m < 8; ++m) qf[m] = *(const bf16x8*)(qb + m * 16);
  }

  floatx16 oacc[4];
#pragma unroll
  for (int j = 0; j < 4; ++j)
#pragma unroll
    for (int r = 0; r < 16; ++r) oacc[j][r] = 0.f;
  float lsum = 0.f;

  const size_t tb = (size_t)(b * 128) * 16384;

  // ---- prime: K(0) -> Kbuf0 ----
  {
    const u16* kb = ksw + tb;
#pragma unroll
    for (int i = 0; i < 4; ++i) {
      const int c = i * 512 + tid;
      GLD_LDS16(kb + (size_t)c * 8, &smem[c * 8]);
    }
  }

  for (int p = 0; p < 128; ++p) {
    // BAR-A: prev iter's LDS reads complete (lgkm only; DMA stays in flight)
    BAR_LGKM();
    // ---- issue V(p) -> Vbuf, then K(p+1) -> Kbuf[(p+1)&1] ----
    {
      const u16* vb = vsw + tb + (size_t)p * 16384;
#pragma unroll
      for (int i = 0; i < 4; ++i) {
        const int c = i * 512 + tid;
        GLD_LDS16(vb + (size_t)c * 8, &Vb[c * 8]);
      }
      const int pn = (p < 127) ? p + 1 : 127;
      const u16* kb = ksw + tb + (size_t)pn * 16384;
      u16* kdst = smem + ((p + 1) & 1) * 16384;
#pragma unroll
      for (int i = 0; i < 4; ++i) {
        const int c = i * 512 + tid;
        GLD_LDS16(kb + (size_t)c * 8, &kdst[c * 8]);
      }
    }
    // BAR-B: vmcnt(8) -> all but newest 8 (V(p)+K(p+1)) retired => K(p) landed
    BAR_VM8();

    // ---- partial S = Q K^T over 128-D k-range (2 chains x 4 MFMA) ----
    const u16* Kb = smem + (p & 1) * 16384;
    floatx16 s0, s1;
#pragma unroll
    for (int r = 0; r < 16; ++r) { s0[r] = 0.f; s1[r] = 0.f; }
#pragma unroll
    for (int m = 0; m < 8; m += 2) {
      const bf16x8 k0 = *(const bf16x8*)&Kb[((dq * 8 + m) * 64 + L) * 8];
      const bf16x8 k1 = *(const bf16x8*)&Kb[((dq * 8 + m + 1) * 64 + L) * 8];
      s0 = __builtin_amdgcn_mfma_f32_32x32x16_bf16(qf[m],     k0, s0, 0, 0, 0);
      s1 = __builtin_amdgcn_mfma_f32_32x32x16_bf16(qf[m + 1], k1, s1, 0, 0, 0);
    }
    // ---- publish partial S (C-layout scatter, stride 34 dwords) ----
#pragma unroll
    for (int r = 0; r < 16; ++r) {
      const int row = (r & 3) + 8 * (r >> 2) + 4 * Lh;
      myreg[row * 34 + Ln] = s0[r] + s1[r];
    }
    // BAR-C: partials visible (lgkm) + V(p) landed (vmcnt(4): only K(p+1) out)
    BAR_LGKM_VM4();

    // ---- rebuild full S in A-layout, exp2 -> P frags in registers ----
    bf16x8 ap[2];
#pragma unroll
    for (int c = 0; c < 2; ++c) {
      const int off = Ln * 34 + c * 16 + Lh * 8;
      union { u16 h[8]; bf16x8 v; } pk;
#pragma unroll
      for (int e = 0; e < 8; e += 2) {
        const float2 a0 = *(const float2*)&r0[off + e];
        const float2 a1 = *(const float2*)&r1[off + e];
        const float2 a2 = *(const float2*)&r2[off + e];
        const float2 a3 = *(const float2*)&r3[off + e];
        const float sx = (a0.x + a1.x) + (a2.x + a3.x);
        const float sy = (a0.y + a1.y) + (a2.y + a3.y);
        const float px = __builtin_amdgcn_exp2f(sx - 17.31234049f);
        const float py = __builtin_amdgcn_exp2f(sy - 17.31234049f);
        lsum += px + py;
        pk.h[e]     = f2bf(px);
        pk.h[e + 1] = f2bf(py);
      }
      ap[c] = pk.v;
    }

    // ---- O += P V over this wave's 128 cols (4 col-tiles x 2 k-steps) ----
#pragma unroll
    for (int j = 0; j < 4; ++j) {
      const int cb = (dq >> 1) * 1024 + ((dq & 1) * 4 + j) * 128;
      const bf16x8 bv0 = *(const bf16x8*)&Vb[(cb + L) * 8];
      const bf16x8 bv1 = *(const bf16x8*)&Vb[(cb + 64 + L) * 8];
      oacc[j] = __builtin_amdgcn_mfma_f32_32x32x16_bf16(ap[0], bv0, oacc[j], 0, 0, 0);
      oacc[j] = __builtin_amdgcn_mfma_f32_32x32x16_bf16(ap[1], bv1, oacc[j], 0, 0, 0);
    }
  }

  // ---- epilogue: row-sum exchange, normalize, store (no O merge) ----
  __syncthreads();                               // full drain; loop done
  const float ltot = lsum + __shfl_xor(lsum, 32);
  float* ls = (float*)smem;                      // reuse Kbuf space
  if (dq == 0 && Lh == 0) ls[qs * 32 + Ln] = ltot;
  __syncthreads();
  float inv[16];
#pragma unroll
  for (int r = 0; r < 16; ++r) {
    const int row = (r & 3) + 8 * (r >> 2) + 4 * Lh;
    inv[r] = 1.0f / ls[qs * 32 + row];
  }
  float* ob = out + ((size_t)(b * 4096 + qt * 64 + qs * 32)) * 512 + dq * 128;
#pragma unroll
  for (int j = 0; j < 4; ++j)
#pragma unroll
    for (int r = 0; r < 16; ++r) {
      const int row = (r & 3) + 8 * (r >> 2) + 4 * Lh;
      ob[(size_t)row * 512 + j * 32 + Ln] = oacc[j][r] * inv[r];
    }
}

// ---------------------------------------------------------------------------
extern "C" void kernel_launch(void* const* d_in, const int* in_sizes, int n_in,
                              void* d_out, int out_size, void* d_ws, size_t ws_size,
                              hipStream_t stream) {
  (void)in_sizes; (void)n_in; (void)out_size; (void)ws_size;
  const float* x  = (const float*)d_in[0];
  const float* Wq = (const float*)d_in[1];
  const float* Wk = (const float*)d_in[2];
  const float* Wv = (const float*)d_in[3];
  float* out = (float*)d_out;
  u16* ws  = (u16*)d_ws;
  u16* qw  = ws;                                  // q row-major [16384][512]
  u16* ksw = qw + (size_t)16384 * 512;            // K swizzled, 16 MB
  u16* vsw = ksw + (size_t)16384 * 512;           // V^T swizzled, 16 MB
  u16* wb  = vsw + (size_t)16384 * 512;           // Wq/Wk/Wv bf16

  // 133120 B dynamic LDS (> default 64K) — set every call; safe under capture.
  (void)hipFuncSetAttribute((const void*)attn,
                            hipFuncAttributeMaxDynamicSharedMemorySize, 133120);

  cvt_w<<<dim3(128, 3), dim3(256), 0, stream>>>(Wq, Wk, Wv, wb);
  qkv_gemm<<<dim3(128, 4, 3), dim3(256), 0, stream>>>(x, wb, qw, ksw, vsw);
  attn<<<dim3(256), dim3(512), 133120, stream>>>(qw, ksw, vsw, out);
}

// Round 7
// 394.205 us; speedup vs baseline: 1.0018x; 1.0018x over previous
//
#include <hip/hip_runtime.h>
#include <stdint.h>

typedef unsigned short u16;
typedef __bf16  bf16x8   __attribute__((ext_vector_type(8)));
typedef float   floatx4  __attribute__((ext_vector_type(4)));
typedef float   floatx16 __attribute__((ext_vector_type(16)));
typedef unsigned short ushortx4 __attribute__((ext_vector_type(4)));

__device__ __forceinline__ u16 f2bf(float f) {
  unsigned u = __builtin_bit_cast(unsigned, f);
  u += 0x7FFFu + ((u >> 16) & 1u);           // RNE; inputs are finite
  return (u16)(u >> 16);
}

#define GLD_LDS16(g, l)                                                        \
  __builtin_amdgcn_global_load_lds(                                            \
      (const __attribute__((address_space(1))) void*)(g),                      \
      (__attribute__((address_space(3))) void*)(l), 16, 0, 0)

// Raw barriers that do NOT drain vmcnt(0) — prefetch DMA stays in flight.
#define BAR_LGKM() asm volatile("s_waitcnt lgkmcnt(0)\ns_barrier" ::: "memory")
#define BAR_VM4()  asm volatile("s_waitcnt vmcnt(4)\ns_barrier" ::: "memory")
#define CFENCE()   asm volatile("" ::: "memory")

// ---------------------------------------------------------------------------
// Kernel 0: weights fp32 -> bf16 (unchanged; works).
// ---------------------------------------------------------------------------
__global__ __launch_bounds__(256) void cvt_w(
    const float* __restrict__ Wq, const float* __restrict__ Wk,
    const float* __restrict__ Wv, u16* __restrict__ dst)
{
  const int z = blockIdx.y;
  const float* src = (z == 0) ? Wq : (z == 1) ? Wk : Wv;
  u16* d = dst + (size_t)z * 262144;
  const int idx = (blockIdx.x * 256 + threadIdx.x) * 8;
  const float4 lo = *(const float4*)&src[idx];
  const float4 hi = *(const float4*)&src[idx + 4];
  union { u16 h[8]; uint4 v; } pk;
  pk.h[0] = f2bf(lo.x); pk.h[1] = f2bf(lo.y); pk.h[2] = f2bf(lo.z); pk.h[3] = f2bf(lo.w);
  pk.h[4] = f2bf(hi.x); pk.h[5] = f2bf(hi.y); pk.h[6] = f2bf(hi.z); pk.h[7] = f2bf(hi.w);
  *(uint4*)&d[idx] = pk.v;
}

// ---------------------------------------------------------------------------
// Kernel 1: fused QKV projection (unchanged from r4/r5/r6; verified).
// K/V^T written frag-major swizzled; q row-major pre-scaled by log2e/sqrt(512).
// ---------------------------------------------------------------------------
__global__ __launch_bounds__(256, 2) void qkv_gemm(
    const float* __restrict__ X, const u16* __restrict__ Wb,
    u16* __restrict__ qo, u16* __restrict__ ksw, u16* __restrict__ vsw)
{
  __shared__ u16 As[128 * 32];
  __shared__ u16 Bs[128 * 32];

  const int tid = threadIdx.x;
  const int w  = tid >> 6, l = tid & 63;
  const int lr = l & 15, lq = l >> 4;
  const int lk = lq * 8;
  const int m0 = blockIdx.x * 128;
  const int n0 = blockIdx.y * 128;
  const int z  = blockIdx.z;
  const u16* W = Wb + (size_t)z * 262144;
  const int wm = (w & 1) * 64, wn = (w >> 1) * 64;

  floatx4 acc[4][4];
  const floatx4 fz = {0.f, 0.f, 0.f, 0.f};
#pragma unroll
  for (int i = 0; i < 4; ++i)
#pragma unroll
    for (int j = 0; j < 4; ++j) acc[i][j] = fz;

  for (int kk = 0; kk < 512; kk += 32) {
    __syncthreads();
#pragma unroll
    for (int i = 0; i < 2; ++i) {
      const int c   = tid * 2 + i;
      const int row = c >> 2;
      const int c8  = (c & 3) * 8;
      const float4 lo = *(const float4*)&X[(size_t)(m0 + row) * 512 + kk + c8];
      const float4 hi = *(const float4*)&X[(size_t)(m0 + row) * 512 + kk + c8 + 4];
      union { u16 h[8]; uint4 v; } pk;
      pk.h[0] = f2bf(lo.x); pk.h[1] = f2bf(lo.y); pk.h[2] = f2bf(lo.z); pk.h[3] = f2bf(lo.w);
      pk.h[4] = f2bf(hi.x); pk.h[5] = f2bf(hi.y); pk.h[6] = f2bf(hi.z); pk.h[7] = f2bf(hi.w);
      *(uint4*)&As[c * 8] = pk.v;
    }
#pragma unroll
    for (int i = 0; i < 2; ++i) {
      const int c = i * 256 + tid;
      GLD_LDS16(W + (size_t)(n0 + (c >> 2)) * 512 + kk + (c & 3) * 8, &Bs[c * 8]);
    }
    __syncthreads();

    bf16x8 af[4], bfr[4];
#pragma unroll
    for (int t = 0; t < 4; ++t) {
      af[t]  = *(const bf16x8*)&As[(wm + t * 16 + lr) * 32 + lk];
      bfr[t] = *(const bf16x8*)&Bs[(wn + t * 16 + lr) * 32 + lk];
    }
#pragma unroll
    for (int i = 0; i < 4; ++i)
#pragma unroll
      for (int j = 0; j < 4; ++j)
        acc[i][j] = __builtin_amdgcn_mfma_f32_16x16x32_bf16(af[i], bfr[j],
                                                            acc[i][j], 0, 0, 0);
  }

  const int cr = lq * 4;   // C layout: col=lane&15, row=quad*4+reg
  if (z == 2) {
#pragma unroll
    for (int i = 0; i < 4; ++i)
#pragma unroll
      for (int j = 0; j < 4; ++j) {
        const int n = n0 + wn + j * 16 + lr;           // d
        const int m = m0 + wm + i * 16 + cr;           // first key (b*4096+s)
        const int b = m >> 12, s = m & 4095;
        const int t = s >> 5, s5 = s & 31;
        const int dh = n >> 8, dl = n & 255;
        const size_t chunk = ((size_t)(b * 128 + t) * 2 + dh) * 1024
                           + (dl >> 5) * 128 + ((s5 >> 4) & 1) * 64
                           + ((s5 >> 3) & 1) * 32 + (dl & 31);
        ushortx4 pk;
#pragma unroll
        for (int r = 0; r < 4; ++r) pk[r] = f2bf(acc[i][j][r]);
        *(ushortx4*)&vsw[chunk * 8 + (cr & 7)] = pk;
      }
  } else if (z == 1) {
#pragma unroll
    for (int i = 0; i < 4; ++i)
#pragma unroll
      for (int j = 0; j < 4; ++j) {
        const int n = n0 + wn + j * 16 + lr;           // d
        const int m = m0 + wm + i * 16 + cr;           // key
        const int b = m >> 12, s = m & 4095;
        const int t = s >> 5, s5 = s & 31;
        const size_t base = (size_t)(b * 128 + t) * 2048
                          + (n >> 4) * 64 + ((n >> 3) & 1) * 32 + s5;
#pragma unroll
        for (int r = 0; r < 4; ++r)
          ksw[(base + r) * 8 + (n & 7)] = f2bf(acc[i][j][r]);
      }
  } else {
    const float sc = 0.06375871732f;                   // log2(e)/sqrt(512)
#pragma unroll
    for (int i = 0; i < 4; ++i)
#pragma unroll
      for (int j = 0; j < 4; ++j) {
        const int m = m0 + wm + i * 16 + cr;
        const int n = n0 + wn + j * 16 + lr;
#pragma unroll
        for (int r = 0; r < 4; ++r)
          qo[(size_t)(m + r) * 512 + n] = f2bf(acc[i][j][r] * sc);
      }
  }
}

// ---------------------------------------------------------------------------
// Kernel 2: flash attention v7.  Grid 256 (1 WG/CU), 512 thr = 8 waves
// (qs in {0,1} q-subtile, dq in {0..3}).  32-key tiles, 128 iters.
// QK: 4-way k-split (8 MFMA/wave); every wave publishes its 16 partial-S
// C-slots to LDS; after barrier each wave softmaxes only its OWN 4-row
// quarter (r = dq*4..+3): 16 b32 reads + 4 exp2 + 4 P-writes — no
// duplication (r6's mistake), no idle waves (r5's).  PV: wave owns d-range
// dq*128 (4 col-tiles x 2 k-steps = 8 MFMA); V B-frags loaded DIRECTLY
// global->VGPR from frag-major vsw (lane-contiguous), issued BEFORE the
// K-prefetch DMA so BAR_VM4 covers both (compiler V-use waits are no-ops).
// K double-buffered via global_load_lds; barriers never drain vmcnt(0).
// (qs,dq) owns a disjoint O block -> no epilogue merge.
// LDS 103424 B: Kbuf 2x32K | Sx 8x4K | P 2x2.5K.
// ---------------------------------------------------------------------------
__global__ __launch_bounds__(512, 2) void attn(
    const u16* __restrict__ q, const u16* __restrict__ ksw,
    const u16* __restrict__ vsw, float* __restrict__ out)
{
  extern __shared__ u16 smem[];
  const int tid = threadIdx.x;
  const int w  = tid >> 6, L = tid & 63;
  const int Ln = L & 31, Lh = L >> 5;
  const int qs = w >> 2, dq = w & 3;
  const int g  = blockIdx.x;
  const int b  = (g & 7) >> 1;                  // XCD-locality: same b per XCD
  const int qt = ((g >> 3) << 1) | (g & 1);     // 0..63

  // LDS map (u16 units): Kbuf 2x16384 | Sx 8x2048 @32768 | P 2x1280 @49152
  float* sxOwn = (float*)(smem + 32768 + (qs * 4 + dq) * 2048);
  const float* sx0 = (const float*)(smem + 32768 + (qs * 4 + 0) * 2048);
  const float* sx1 = (const float*)(smem + 32768 + (qs * 4 + 1) * 2048);
  const float* sx2 = (const float*)(smem + 32768 + (qs * 4 + 2) * 2048);
  const float* sx3 = (const float*)(smem + 32768 + (qs * 4 + 3) * 2048);
  u16* pReg = smem + 49152 + qs * 1280;         // 32 rows x 40 u16

  // ---- Q A-frags for this wave's 128-D k-range: 8 x bf16x8 (32 VGPR) ----
  bf16x8 qf[8];
  {
    const u16* qb = q + ((size_t)(b * 4096 + qt * 64 + qs * 32 + Ln)) * 512
                    + dq * 128 + Lh * 8;
#pragma unroll
    for (int m = 0; m < 8; ++m) qf[m] = *(const bf16x8*)(qb + m * 16);
  }

  floatx16 oacc[4];
#pragma unroll
  for (int j = 0; j < 4; ++j)
#pragma unroll
    for (int r = 0; r < 16; ++r) oacc[j][r] = 0.f;
  float lsum[4] = {0.f, 0.f, 0.f, 0.f};

  const size_t tkb = (size_t)(b * 128) * 16384;  // ksw u16 base for batch

  // ---- prime: K(0) -> Kbuf0 (32KB, 4 chunks/thread) ----
#pragma unroll
  for (int i = 0; i < 4; ++i) {
    const int c = i * 512 + tid;
    GLD_LDS16(ksw + tkb + (size_t)c * 8, &smem[c * 8]);
  }

  for (int p = 0; p < 128; ++p) {
    // BAR-A: prev iter's LDS reads retired (lgkm only; DMA stays in flight)
    BAR_LGKM();

    // ---- V B-frags: direct global->VGPR (lane-contiguous, 8 loads) ----
    bf16x8 vf[8];
#pragma unroll
    for (int ct = 0; ct < 4; ++ct) {
      const int g4 = dq * 4 + ct;               // d 32-block 0..15
      const u16* vr = vsw + ((size_t)(b * 128 + p) * 2 + (g4 >> 3)) * 8192
                      + (size_t)((g4 & 7) * 128) * 8;
      vf[ct * 2 + 0] = *(const bf16x8*)(vr + (size_t)L * 8);
      vf[ct * 2 + 1] = *(const bf16x8*)(vr + (size_t)(64 + L) * 8);
    }
    CFENCE();                                   // keep V loads before K DMA
    // ---- K(p+1) prefetch DMA -> Kbuf[(p+1)&1] ----
    {
      const int pn = (p < 127) ? p + 1 : 127;
      const u16* kb = ksw + tkb + (size_t)pn * 16384;
      u16* kdst = smem + ((p + 1) & 1) * 16384;
#pragma unroll
      for (int i = 0; i < 4; ++i) {
        const int c = i * 512 + tid;
        GLD_LDS16(kb + (size_t)c * 8, &kdst[c * 8]);
      }
    }
    // BAR-B: vmcnt(4) -> only K(p+1)'s 4 outstanding => K(p), V(p) landed
    BAR_VM4();

    // ---- partial S = Q K^T over this wave's 128-D k-range (8 MFMA) ----
    const u16* Kb = smem + (p & 1) * 16384;
    floatx16 s0, s1;
#pragma unroll
    for (int r = 0; r < 16; ++r) { s0[r] = 0.f; s1[r] = 0.f; }
#pragma unroll
    for (int m = 0; m < 8; m += 2) {
      const bf16x8 k0 = *(const bf16x8*)&Kb[((dq * 8 + m) * 64 + L) * 8];
      const bf16x8 k1 = *(const bf16x8*)&Kb[((dq * 8 + m + 1) * 64 + L) * 8];
      s0 = __builtin_amdgcn_mfma_f32_32x32x16_bf16(qf[m],     k0, s0, 0, 0, 0);
      s1 = __builtin_amdgcn_mfma_f32_32x32x16_bf16(qf[m + 1], k1, s1, 0, 0, 0);
    }
    // ---- publish all 16 partial C-slots (b32, 2-way bank alias = free) ----
#pragma unroll
    for (int r = 0; r < 16; ++r) sxOwn[r * 64 + L] = s0[r] + s1[r];
    // BAR-C: partials visible
    BAR_LGKM();

    // ---- softmax: own 4-row quarter only (r = dq*4 + j) ----
#pragma unroll
    for (int j = 0; j < 4; ++j) {
      const int r = dq * 4 + j;
      const float tot = (sx0[r * 64 + L] + sx1[r * 64 + L])
                      + (sx2[r * 64 + L] + sx3[r * 64 + L]);
      const float pe = __builtin_amdgcn_exp2f(tot - 17.31234049f);
      lsum[j] += pe;
      const int row = (r & 3) + 8 * (r >> 2) + 4 * Lh;
      pReg[row * 40 + Ln] = f2bf(pe);
    }
    // BAR-D: P visible
    BAR_LGKM();

    // ---- O += P V over this wave's 128 cols (4 col-tiles x 2 k-steps) ----
    const bf16x8 ap0 = *(const bf16x8*)&pReg[Ln * 40 + Lh * 8];
    const bf16x8 ap1 = *(const bf16x8*)&pReg[Ln * 40 + 16 + Lh * 8];
#pragma unroll
    for (int ct = 0; ct < 4; ++ct) {
      oacc[ct] = __builtin_amdgcn_mfma_f32_32x32x16_bf16(ap0, vf[ct * 2 + 0],
                                                         oacc[ct], 0, 0, 0);
      oacc[ct] = __builtin_amdgcn_mfma_f32_32x32x16_bf16(ap1, vf[ct * 2 + 1],
                                                         oacc[ct], 0, 0, 0);
    }
  }

  // ---- epilogue: row-sum butterfly, normalize, store (no O merge) ----
  __syncthreads();                               // full drain (loop done)
  float* ls = (float*)(smem + 32768);            // Sx space, DMA-free
#pragma unroll
  for (int j = 0; j < 4; ++j) {
    float s = lsum[j];
    s += __shfl_xor(s, 1, 32);
    s += __shfl_xor(s, 2, 32);
    s += __shfl_xor(s, 4, 32);
    s += __shfl_xor(s, 8, 32);
    s += __shfl_xor(s, 16, 32);
    if (Ln == 0) {
      const int r = dq * 4 + j;
      ls[qs * 32 + (r & 3) + 8 * (r >> 2) + 4 * Lh] = s;
    }
  }
  __syncthreads();
  float inv[16];
#pragma unroll
  for (int r = 0; r < 16; ++r)
    inv[r] = 1.0f / ls[qs * 32 + (r & 3) + 8 * (r >> 2) + 4 * Lh];
  float* ob = out + ((size_t)(b * 4096 + qt * 64 + qs * 32)) * 512 + dq * 128;
#pragma unroll
  for (int ct = 0; ct < 4; ++ct)
#pragma unroll
    for (int r = 0; r < 16; ++r) {
      const int row = (r & 3) + 8 * (r >> 2) + 4 * Lh;
      ob[(size_t)row * 512 + ct * 32 + Ln] = oacc[ct][r] * inv[r];
    }
}

// ---------------------------------------------------------------------------
extern "C" void kernel_launch(void* const* d_in, const int* in_sizes, int n_in,
                              void* d_out, int out_size, void* d_ws, size_t ws_size,
                              hipStream_t stream) {
  (void)in_sizes; (void)n_in; (void)out_size; (void)ws_size;
  const float* x  = (const float*)d_in[0];
  const float* Wq = (const float*)d_in[1];
  const float* Wk = (const float*)d_in[2];
  const float* Wv = (const float*)d_in[3];
  float* out = (float*)d_out;
  u16* ws  = (u16*)d_ws;
  u16* qw  = ws;                                  // q row-major [16384][512]
  u16* ksw = qw + (size_t)16384 * 512;            // K swizzled, 16 MB
  u16* vsw = ksw + (size_t)16384 * 512;           // V^T swizzled, 16 MB
  u16* wb  = vsw + (size_t)16384 * 512;           // Wq/Wk/Wv bf16

  // 103424 B dynamic LDS (> default 64K) — set every call; safe under capture.
  (void)hipFuncSetAttribute((const void*)attn,
                            hipFuncAttributeMaxDynamicSharedMemorySize, 103424);

  cvt_w<<<dim3(128, 3), dim3(256), 0, stream>>>(Wq, Wk, Wv, wb);
  qkv_gemm<<<dim3(128, 4, 3), dim3(256), 0, stream>>>(x, wb, qw, ksw, vsw);
  attn<<<dim3(256), dim3(512), 103424, stream>>>(qw, ksw, vsw, out);
}